// Round 9
// baseline (138.956 us; speedup 1.0000x reference)
//
#include <hip/hip_runtime.h>

typedef __attribute__((ext_vector_type(4))) float f32x4;
typedef __attribute__((ext_vector_type(4))) int i32x4;
typedef __attribute__((ext_vector_type(8))) short short8;
typedef unsigned int u32;
typedef unsigned long long u64;
typedef unsigned short u16;

#define NB 512
#define TT 256
#define CC 384
#define HH 64
// ws layout: WbT (147456 B) | Qf (16.78 MB) | Kf (16.78 MB) | Vt (16.78 MB)
#define WS_NEED 50479104ull

__device__ __forceinline__ u16 fbf(float f) {
    u32 u = __builtin_bit_cast(u32, f);
    u32 r = u + 0x7fffu + ((u >> 16) & 1u);
    return (u16)(r >> 16);
}

__device__ __forceinline__ u32 cvtpk(float lo, float hi) {
    u32 r;
    asm("v_cvt_pk_bf16_f32 %0, %1, %2" : "=v"(r) : "v"(lo), "v"(hi));
    return r;
}

__device__ __forceinline__ f32x4 mfma16x16x32(short8 a, short8 b, f32x4 c) {
    return __builtin_amdgcn_mfma_f32_16x16x32_bf16(a, b, c, 0, 0, 0);
}

__device__ __forceinline__ short8 load_afr(const float* p) {
    f32x4 f0 = *(const f32x4*)p;
    f32x4 f1 = *(const f32x4*)(p + 4);
    i32x4 aw = {(int)cvtpk(f0[0], f0[1]), (int)cvtpk(f0[2], f0[3]),
                (int)cvtpk(f1[0], f1[1]), (int)cvtpk(f1[2], f1[3])};
    return __builtin_bit_cast(short8, aw);
}

// WbT layout: fragment fi = ((mat*12 + kt)*4 + nt); element (fi*64 + lane)*8 + j
//   = W[mat][c = 32*kt + 8*(lane>>4) + j][h = 16*nt + (lane&15)]
// mat 0 = Wq * 384^-0.5 (scale folded), 1 = Wk, 2 = Wv.
__global__ __launch_bounds__(256) void prep_w(const float* __restrict__ Wk,
                                              const float* __restrict__ Wq,
                                              const float* __restrict__ Wv,
                                              u16* __restrict__ WbT) {
    int t = blockIdx.x * 256 + threadIdx.x;
    if (t >= 144 * 64) return;
    int lane = t & 63;
    int fi = t >> 6;
    int mat = fi / 48;
    int kt = (fi >> 2) % 12;
    int nt = fi & 3;
    const float* W = (mat == 0) ? Wq : (mat == 1 ? Wk : Wv);
    float scale = (mat == 0) ? 0.05103103630798288f : 1.0f;
    int c0 = 32 * kt + 8 * (lane >> 4);
    int h = 16 * nt + (lane & 15);
#pragma unroll
    for (int j = 0; j < 8; ++j)
        WbT[(size_t)t * 8 + j] = fbf(W[(c0 + j) * HH + h] * scale);
}

// ---------------------------------------------------------------------------
// Kernel 1: projection. 1024 blocks x 256 thr; wave owns 32 rows of one
// half-batch. Pass A (Q,K: 64 AGPR) then pass B (V: 32 AGPR) -> arch+acc
// <= 128 -> 4 waves/SIMD. Q/K transposed to B-fragment layout via 2KB
// per-wave LDS (expression-identical to r7: local row == global row mod 8).
// V written to a per-batch GLOBAL Vt [64h][256s] bf16 with r7's VERBATIM
// u64-pack + (hh&7)<<4 swizzle write (same per-wave 32-s-row coverage).
//   Qf/Kf: [b][tile16][k2][lane64][8]   Vt: [b] + hh*512 + swz(2*s)
// ---------------------------------------------------------------------------
__global__ __launch_bounds__(256, 4) void proj_qkv(const float* __restrict__ x,
                                                   const u16* __restrict__ WbT,
                                                   u16* __restrict__ Qf,
                                                   u16* __restrict__ Kf,
                                                   u16* __restrict__ Vt) {
    __shared__ __align__(16) u16 scr[4][16 * 64];  // 2KB per wave

    const int tid = (int)threadIdx.x;
    const int lane = tid & 63;
    const int v = tid >> 6;
    const int c = lane & 15;
    const int g = lane >> 4;
    const int blk = (int)blockIdx.x;
    const int b = blk >> 1;
    const int r0 = ((blk & 1) << 7) + (v << 5);  // row base, 32 rows per wave

    const float* xb = x + (size_t)b * TT * CC;
    const float* prow0 = xb + (size_t)(r0 + c) * CC + 8 * g;
    const float* prow1 = prow0 + (size_t)16 * CC;
    char* sb = (char*)scr[v];

    // ---- pass A (Q then K): D-layout -> LDS scratch -> fragments ----
#pragma unroll
    for (int mat = 0; mat < 2; ++mat) {
        f32x4 acc[2][4];
#pragma unroll
        for (int hf = 0; hf < 2; ++hf)
#pragma unroll
            for (int nt = 0; nt < 4; ++nt)
                acc[hf][nt] = (f32x4){0.f, 0.f, 0.f, 0.f};

        for (int kt = 0; kt < 12; ++kt) {
            short8 a0 = load_afr(prow0 + 32 * kt);
            short8 a1 = load_afr(prow1 + 32 * kt);
#pragma unroll
            for (int nt = 0; nt < 4; ++nt) {
                short8 bfr = *(const short8*)(WbT + (size_t)(((mat * 12 + kt) * 4 + nt) * 64 + lane) * 8);
                acc[0][nt] = mfma16x16x32(a0, bfr, acc[0][nt]);
                acc[1][nt] = mfma16x16x32(a1, bfr, acc[1][nt]);
            }
        }

        u16* dstM = mat ? Kf : Qf;
#pragma unroll
        for (int hf = 0; hf < 2; ++hf) {
#pragma unroll
            for (int nt = 0; nt < 4; ++nt)
#pragma unroll
                for (int r = 0; r < 4; ++r) {
                    int row = 4 * g + r;
                    *(u16*)(sb + row * 128 + (((16 * nt + c) * 2) ^ ((row & 7) << 4))) = fbf(acc[hf][nt][r]);
                }
#pragma unroll
            for (int k2 = 0; k2 < 2; ++k2) {
                short8 f = *(const short8*)(sb + c * 128 + ((64 * k2 + 16 * g) ^ ((c & 7) << 4)));
                *(short8*)(dstM + (size_t)(((b * 16 + (r0 >> 4) + hf) * 2 + k2) * 64 + lane) * 8) = f;
            }
        }
    }

    // ---- pass B (V): D-layout -> global Vt, r7-verbatim write ----
    {
        f32x4 acc[2][4];
#pragma unroll
        for (int hf = 0; hf < 2; ++hf)
#pragma unroll
            for (int nt = 0; nt < 4; ++nt)
                acc[hf][nt] = (f32x4){0.f, 0.f, 0.f, 0.f};

        for (int kt = 0; kt < 12; ++kt) {
            short8 a0 = load_afr(prow0 + 32 * kt);
            short8 a1 = load_afr(prow1 + 32 * kt);
#pragma unroll
            for (int nt = 0; nt < 4; ++nt) {
                short8 bfr = *(const short8*)(WbT + (size_t)(((2 * 12 + kt) * 4 + nt) * 64 + lane) * 8);
                acc[0][nt] = mfma16x16x32(a0, bfr, acc[0][nt]);
                acc[1][nt] = mfma16x16x32(a1, bfr, acc[1][nt]);
            }
        }

        char* vtb = (char*)Vt + (size_t)b * 32768;
#pragma unroll
        for (int hf = 0; hf < 2; ++hf)
#pragma unroll
            for (int nt = 0; nt < 4; ++nt) {
                int hh = 16 * nt + c;
                int sb4 = r0 + 16 * hf + 4 * g;
                u64 pkv = (u64)cvtpk(acc[hf][nt][0], acc[hf][nt][1]) |
                          ((u64)cvtpk(acc[hf][nt][2], acc[hf][nt][3]) << 32);
                *(u64*)(vtb + hh * 512 + ((sb4 * 2) ^ ((hh & 7) << 4))) = pkv;
            }
    }
}

// ---------------------------------------------------------------------------
// Kernel 2: attention, ZERO LDS. 2048 blocks x 256 thr; each wave owns one
// 16-row q-tile; block's 4 tiles are a balanced causal set (10 chunk-iters
// per block). K/Q read as coalesced fragment loads; V read with r7's
// VERBATIM swizzled Vt fragment-read expression. P reshape via the
// r2-verified shfl+select. All math is a line-for-line r7/r2 transplant.
// ---------------------------------------------------------------------------
__global__ __launch_bounds__(256, 4) void attn_tiles(const u16* __restrict__ Qf,
                                                     const u16* __restrict__ Kf,
                                                     const u16* __restrict__ Vt,
                                                     float* __restrict__ out) {
    const int tid = (int)threadIdx.x;
    const int lane = tid & 63;
    const int v = tid >> 6;
    const int c = lane & 15;
    const int g = lane >> 4;
    const int blk = (int)blockIdx.x;
    const int b = blk >> 2;
    const int j = blk & 3;

    const u32 pw = (j == 0) ? 0x0F0A0500u : (j == 1) ? 0x0E0B0401u
                 : (j == 2) ? 0x0D080702u : 0x0C090603u;
    const int t = (int)((pw >> (8 * v)) & 15u);
    const int gr = 16 * t;
    const int qg = gr + c;
    const int lastc = t >> 2;

    const char* vtb = (const char*)Vt + (size_t)b * 32768;

    short8 Q0 = *(const short8*)(Qf + (size_t)(((b * 16 + t) * 2 + 0) * 64 + lane) * 8);
    short8 Q1 = *(const short8*)(Qf + (size_t)(((b * 16 + t) * 2 + 1) * 64 + lane) * 8);

    float m_run = -1e30f, l_run = 0.f;
    f32x4 o[4];
#pragma unroll
    for (int ht = 0; ht < 4; ++ht)
        o[ht] = (f32x4){0.f, 0.f, 0.f, 0.f};

    const int srcA = c + ((lane & 16) << 1);  // c + 32*(g&1)
    const int srcB = srcA + 16;
    const bool hi = (g & 2) != 0;

    for (int ci = 0; ci <= lastc; ++ci) {
        const int s0 = 64 * ci;
        int stx = (gr + 15 - s0) >> 4;
        const int stmax = stx > 3 ? 3 : stx;
        const bool needMask = (s0 + 63 > gr);

        // S^T = K(16s x 32h) x Q^T; lane: s-row = 4g+r, q-col = c
        f32x4 SS[4];
#pragma unroll
        for (int st = 0; st < 4; ++st)
            SS[st] = (f32x4){0.f, 0.f, 0.f, 0.f};
#pragma unroll
        for (int st = 0; st < 4; ++st)
            if (st <= stmax) {
                const u16* kb = Kf + (size_t)(((b * 16 + 4 * ci + st) * 2) * 64 + lane) * 8;
                short8 kf0 = *(const short8*)kb;
                short8 kf1 = *(const short8*)(kb + 512);
                SS[st] = mfma16x16x32(kf0, Q0, SS[st]);
                SS[st] = mfma16x16x32(kf1, Q1, SS[st]);
            }

        // mask (diagonal chunks only) + chunk max
        float mx = -1e30f;
#pragma unroll
        for (int st = 0; st < 4; ++st)
            if (st <= stmax)
#pragma unroll
                for (int r = 0; r < 4; ++r) {
                    float val = SS[st][r];
                    if (needMask) {
                        int sg = s0 + 16 * st + 4 * g + r;
                        val = (sg > qg) ? -1e30f : val;
                        SS[st][r] = val;
                    }
                    mx = fmaxf(mx, val);
                }
        mx = fmaxf(mx, __shfl_xor(mx, 16));
        mx = fmaxf(mx, __shfl_xor(mx, 32));

        float mn = fmaxf(m_run, mx);
        float fs = __expf(m_run - mn);
        m_run = mn;

        float ls = 0.f;
#pragma unroll
        for (int st = 0; st < 4; ++st)
            if (st <= stmax)
#pragma unroll
                for (int r = 0; r < 4; ++r) {
                    float p = __expf(SS[st][r] - mn);
                    SS[st][r] = p;
                    ls += p;
                }
        ls += __shfl_xor(ls, 16);
        ls += __shfl_xor(ls, 32);
        l_run = l_run * fs + ls;

        if (ci) {
#pragma unroll
            for (int r = 0; r < 4; ++r) {
                float fr = __shfl(fs, 4 * g + r);
#pragma unroll
                for (int ht = 0; ht < 4; ++ht)
                    o[ht][r] *= fr;
            }
        }

        // pk[st][w]: bf16 pair P[q=c][s=16st+4g+2w+{0,1}]; SS[st>stmax]==0 -> 0
        u32 pk[4][2];
#pragma unroll
        for (int st = 0; st < 4; ++st) {
            pk[st][0] = cvtpk(SS[st][0], SS[st][1]);
            pk[st][1] = cvtpk(SS[st][2], SS[st][3]);
        }

        // PV: Pf word i of lane(g,c) = pk[2ks+(g>>1)][i&1] from lane srcA/srcB
        const int ksmax = stmax >> 1;
#pragma unroll
        for (int ks = 0; ks < 2; ++ks)
            if (ks <= ksmax) {
                u32 A0 = (u32)__shfl((int)pk[2 * ks][0], srcA), B0 = (u32)__shfl((int)pk[2 * ks + 1][0], srcA);
                u32 A1 = (u32)__shfl((int)pk[2 * ks][1], srcA), B1 = (u32)__shfl((int)pk[2 * ks + 1][1], srcA);
                u32 A2 = (u32)__shfl((int)pk[2 * ks][0], srcB), B2 = (u32)__shfl((int)pk[2 * ks + 1][0], srcB);
                u32 A3 = (u32)__shfl((int)pk[2 * ks][1], srcB), B3 = (u32)__shfl((int)pk[2 * ks + 1][1], srcB);
                i32x4 tw = {(int)(hi ? B0 : A0), (int)(hi ? B1 : A1),
                            (int)(hi ? B2 : A2), (int)(hi ? B3 : A3)};
                short8 Pf = __builtin_bit_cast(short8, tw);
#pragma unroll
                for (int ht = 0; ht < 4; ++ht) {
                    int hh = 16 * ht + c;
                    short8 vf = *(const short8*)(vtb + hh * 512 + ((2 * s0 + 64 * ks + 16 * g) ^ ((hh & 7) << 4)));
                    o[ht] = mfma16x16x32(Pf, vf, o[ht]);
                }
            }
    }

    float ri = 1.f / l_run;
    float* ob = out + ((size_t)b * TT + gr) * HH;
#pragma unroll
    for (int r = 0; r < 4; ++r) {
        float rr = __shfl(ri, 4 * g + r);
#pragma unroll
        for (int ht = 0; ht < 4; ++ht)
            ob[(4 * g + r) * HH + 16 * ht + c] = o[ht][r] * rr;
    }
}

// ---------------------------------------------------------------------------
// Fallback fused kernel (round-7, proven): used only if ws_size < WS_NEED.
// ---------------------------------------------------------------------------
__global__ __launch_bounds__(512, 2) void attn_head(const float* __restrict__ x,
                                                    const u16* __restrict__ WbT,
                                                    float* __restrict__ out) {
    __shared__ __align__(16) u16 Klds[TT * HH];
    __shared__ __align__(16) u16 Vtlds[HH * TT];
    __shared__ __align__(16) u16 Pscr[8 * 16 * 64];

    const int tid = (int)threadIdx.x;
    const int lane = tid & 63;
    const int w = tid >> 6;
    const int c = lane & 15;
    const int g = lane >> 4;
    const int b = (int)blockIdx.x;
    const int gr = 32 * (w < 4 ? w : 11 - w);

    char* kbase = (char*)Klds;
    char* vbase = (char*)Vtlds;
    char* sbase = (char*)(Pscr + w * 1024);
    const float* xb = x + (size_t)b * TT * CC;
    const float* prow0 = xb + (size_t)(gr + c) * CC + 8 * g;
    const float* prow1 = xb + (size_t)(gr + 16 + c) * CC + 8 * g;

    short8 Qfr[2][2];

    {
        f32x4 acc[2][2][4];
#pragma unroll
        for (int m = 0; m < 2; ++m)
#pragma unroll
            for (int h = 0; h < 2; ++h)
#pragma unroll
                for (int nt = 0; nt < 4; ++nt)
                    acc[m][h][nt] = (f32x4){0.f, 0.f, 0.f, 0.f};

        for (int kt = 0; kt < 12; ++kt) {
            short8 a0 = load_afr(prow0 + 32 * kt);
            short8 a1 = load_afr(prow1 + 32 * kt);
#pragma unroll
            for (int mat = 0; mat < 2; ++mat)
#pragma unroll
                for (int nt = 0; nt < 4; ++nt) {
                    short8 bfr = *(const short8*)(WbT + (size_t)(((mat * 12 + kt) * 4 + nt) * 64 + lane) * 8);
                    acc[mat][0][nt] = mfma16x16x32(a0, bfr, acc[mat][0][nt]);
                    acc[mat][1][nt] = mfma16x16x32(a1, bfr, acc[mat][1][nt]);
                }
        }

#pragma unroll
        for (int h = 0; h < 2; ++h) {
            const int qr = gr + 16 * h;
#pragma unroll
            for (int nt = 0; nt < 4; ++nt)
#pragma unroll
                for (int r = 0; r < 4; ++r) {
                    int q = qr + 4 * g + r;
                    int hh = 16 * nt + c;
                    *(u16*)(kbase + q * 128 + ((hh * 2) ^ ((q & 7) << 4))) = fbf(acc[0][h][nt][r]);
                }
#pragma unroll
            for (int kt = 0; kt < 2; ++kt) {
                int q = qr + c;
                Qfr[h][kt] = *(const short8*)(kbase + q * 128 + ((64 * kt + 16 * g) ^ ((q & 7) << 4)));
            }
        }

#pragma unroll
        for (int h = 0; h < 2; ++h)
#pragma unroll
            for (int nt = 0; nt < 4; ++nt) {
                int hh = 16 * nt + c;
#pragma unroll
                for (int r = 0; r < 4; ++r) {
                    int s = gr + 16 * h + 4 * g + r;
                    *(u16*)(kbase + s * 128 + ((hh * 2) ^ ((s & 7) << 4))) = fbf(acc[1][h][nt][r]);
                }
            }
    }

    {
        f32x4 accV[2][4];
#pragma unroll
        for (int h = 0; h < 2; ++h)
#pragma unroll
            for (int nt = 0; nt < 4; ++nt)
                accV[h][nt] = (f32x4){0.f, 0.f, 0.f, 0.f};

        for (int kt = 0; kt < 12; ++kt) {
            short8 a0 = load_afr(prow0 + 32 * kt);
            short8 a1 = load_afr(prow1 + 32 * kt);
#pragma unroll
            for (int nt = 0; nt < 4; ++nt) {
                short8 bfr = *(const short8*)(WbT + (size_t)(((2 * 12 + kt) * 4 + nt) * 64 + lane) * 8);
                accV[0][nt] = mfma16x16x32(a0, bfr, accV[0][nt]);
                accV[1][nt] = mfma16x16x32(a1, bfr, accV[1][nt]);
            }
        }

#pragma unroll
        for (int h = 0; h < 2; ++h)
#pragma unroll
            for (int nt = 0; nt < 4; ++nt) {
                int hh = 16 * nt + c;
                int sb4 = gr + 16 * h + 4 * g;
                u64 pkv = (u64)cvtpk(accV[h][nt][0], accV[h][nt][1]) |
                          ((u64)cvtpk(accV[h][nt][2], accV[h][nt][3]) << 32);
                *(u64*)(vbase + hh * 512 + ((sb4 * 2) ^ ((hh & 7) << 4))) = pkv;
            }
    }

    __syncthreads();

    const int lastc = (gr + 31) >> 6;
    const int qg0 = gr + c, qg1 = gr + 16 + c;

    float m0r = -1e30f, l0r = 0.f, m1r = -1e30f, l1r = 0.f;
    f32x4 o[2][4];
#pragma unroll
    for (int h = 0; h < 2; ++h)
#pragma unroll
        for (int ht = 0; ht < 4; ++ht)
            o[h][ht] = (f32x4){0.f, 0.f, 0.f, 0.f};

    for (int ci = 0; ci <= lastc; ++ci) {
        const int s0 = 64 * ci;
        int stx = (gr + 31 - s0) >> 4;
        const int stmax = stx > 3 ? 3 : stx;
        const bool needMask = (s0 + 63 > gr);

        f32x4 SS[4][2];
#pragma unroll
        for (int st = 0; st < 4; ++st) {
            SS[st][0] = (f32x4){0.f, 0.f, 0.f, 0.f};
            SS[st][1] = (f32x4){0.f, 0.f, 0.f, 0.f};
        }
#pragma unroll
        for (int kt = 0; kt < 2; ++kt)
#pragma unroll
            for (int st = 0; st < 4; ++st)
                if (st <= stmax) {
                    int s = s0 + 16 * st + c;
                    short8 kf = *(const short8*)(kbase + s * 128 + ((64 * kt + 16 * g) ^ ((s & 7) << 4)));
                    SS[st][0] = mfma16x16x32(kf, Qfr[0][kt], SS[st][0]);
                    SS[st][1] = mfma16x16x32(kf, Qfr[1][kt], SS[st][1]);
                }

        float mx0 = -1e30f, mx1 = -1e30f;
#pragma unroll
        for (int st = 0; st < 4; ++st)
            if (st <= stmax)
#pragma unroll
                for (int r = 0; r < 4; ++r) {
                    float v0 = SS[st][0][r], v1 = SS[st][1][r];
                    if (needMask) {
                        int sg = s0 + 16 * st + 4 * g + r;
                        v0 = (sg > qg0) ? -1e30f : v0;
                        v1 = (sg > qg1) ? -1e30f : v1;
                        SS[st][0][r] = v0;
                        SS[st][1][r] = v1;
                    }
                    mx0 = fmaxf(mx0, v0);
                    mx1 = fmaxf(mx1, v1);
                }
        mx0 = fmaxf(mx0, __shfl_xor(mx0, 16));
        mx0 = fmaxf(mx0, __shfl_xor(mx0, 32));
        mx1 = fmaxf(mx1, __shfl_xor(mx1, 16));
        mx1 = fmaxf(mx1, __shfl_xor(mx1, 32));

        float mn0 = fmaxf(m0r, mx0), mn1 = fmaxf(m1r, mx1);
        float fs0 = __expf(m0r - mn0), fs1 = __expf(m1r - mn1);
        m0r = mn0;
        m1r = mn1;

        float ls0 = 0.f, ls1 = 0.f;
#pragma unroll
        for (int st = 0; st < 4; ++st)
            if (st <= stmax)
#pragma unroll
                for (int r = 0; r < 4; ++r) {
                    float p0 = __expf(SS[st][0][r] - mn0);
                    float p1 = __expf(SS[st][1][r] - mn1);
                    SS[st][0][r] = p0;
                    SS[st][1][r] = p1;
                    ls0 += p0;
                    ls1 += p1;
                }
        ls0 += __shfl_xor(ls0, 16);
        ls0 += __shfl_xor(ls0, 32);
        ls1 += __shfl_xor(ls1, 16);
        ls1 += __shfl_xor(ls1, 32);
        l0r = l0r * fs0 + ls0;
        l1r = l1r * fs1 + ls1;

        if (ci) {
#pragma unroll
            for (int r = 0; r < 4; ++r) {
                float fr0 = __shfl(fs0, 4 * g + r);
                float fr1 = __shfl(fs1, 4 * g + r);
#pragma unroll
                for (int ht = 0; ht < 4; ++ht) {
                    o[0][ht][r] *= fr0;
                    o[1][ht][r] *= fr1;
                }
            }
        }

        const int ksmax = stmax >> 1;
#pragma unroll
        for (int h = 0; h < 2; ++h) {
#pragma unroll
            for (int st = 0; st < 4; ++st)
                if (st <= stmax) {
                    u64 pp = (u64)cvtpk(SS[st][h][0], SS[st][h][1]) |
                             ((u64)cvtpk(SS[st][h][2], SS[st][h][3]) << 32);
                    *(u64*)(sbase + c * 128 + ((32 * st + 8 * g) ^ ((c & 7) << 4))) = pp;
                }
#pragma unroll
            for (int ks = 0; ks < 2; ++ks)
                if (ks <= ksmax) {
                    short8 Pf = *(const short8*)(sbase + c * 128 + ((64 * ks + 16 * g) ^ ((c & 7) << 4)));
#pragma unroll
                    for (int ht = 0; ht < 4; ++ht) {
                        int hh = 16 * ht + c;
                        short8 vf = *(const short8*)(vbase + hh * 512 + ((2 * s0 + 64 * ks + 16 * g) ^ ((hh & 7) << 4)));
                        o[h][ht] = mfma16x16x32(Pf, vf, o[h][ht]);
                    }
                }
        }
    }

    float ri0 = 1.f / l0r, ri1 = 1.f / l1r;
    float* ob0 = out + ((size_t)b * TT + gr) * HH;
    float* ob1 = ob0 + 16 * HH;
#pragma unroll
    for (int r = 0; r < 4; ++r) {
        float rr0 = __shfl(ri0, 4 * g + r);
        float rr1 = __shfl(ri1, 4 * g + r);
#pragma unroll
        for (int ht = 0; ht < 4; ++ht) {
            ob0[(4 * g + r) * HH + 16 * ht + c] = o[0][ht][r] * rr0;
            ob1[(4 * g + r) * HH + 16 * ht + c] = o[1][ht][r] * rr1;
        }
    }
}

extern "C" void kernel_launch(void* const* d_in, const int* in_sizes, int n_in,
                              void* d_out, int out_size, void* d_ws, size_t ws_size,
                              hipStream_t stream) {
    (void)in_sizes; (void)n_in; (void)out_size;
    const float* x = (const float*)d_in[0];
    const float* Wk = (const float*)d_in[1];
    const float* Wq = (const float*)d_in[2];
    const float* Wv = (const float*)d_in[3];
    u16* WbT = (u16*)d_ws;
    float* out = (float*)d_out;

    prep_w<<<36, 256, 0, stream>>>(Wk, Wq, Wv, WbT);

    if (ws_size >= WS_NEED) {
        u16* Qf = WbT + 73728;           // byte 147456
        u16* Kf = Qf + 8388608;
        u16* Vt = Kf + 8388608;
        proj_qkv<<<NB * 2, 256, 0, stream>>>(x, WbT, Qf, Kf, Vt);
        attn_tiles<<<NB * 4, 256, 0, stream>>>(Qf, Kf, Vt, out);
    } else {
        attn_head<<<NB, 512, 0, stream>>>(x, WbT, out);
    }
}